// Round 1
// baseline (1446.343 us; speedup 1.0000x reference)
//
#include <hip/hip_runtime.h>
#include <cstdint>
#include <cstddef>

#define B_N 4096
// ws layout (float units)
static constexpr size_t H2_OFF     = 0;                                  // 4096*4096 f
static constexpr size_t POOLED_OFF = (size_t)B_N * 4096;                 // B*16 f
static constexpr size_t EIDX_OFF   = POOLED_OFF + (size_t)B_N * 16;      // B int
static constexpr size_t EW_OFF     = EIDX_OFF + B_N;                     // B f
static constexpr size_t ORDER_OFF  = EW_OFF + B_N;                       // 4*B int
static constexpr size_t CNT_OFF    = ORDER_OFF + (size_t)4 * B_N;        // 4 int
static constexpr size_t PSUM_OFF   = CNT_OFF + 4;                        // 4 f

// ---------------- K1: router conv(3->16,SAME) + relu + global avg pool ----------------
__global__ __launch_bounds__(256) void k_router_conv(const float* __restrict__ x,
    const float* __restrict__ gw, const float* __restrict__ gb,
    float* __restrict__ pooled) {
  __shared__ __align__(16) float xpad[3 * 34 * 34];   // zero-padded image
  __shared__ float red[16 * 17];
  const int b = blockIdx.x, t = threadIdx.x;
  for (int i = t; i < 3 * 34 * 34; i += 256) xpad[i] = 0.f;
  __syncthreads();
  const float4* x4 = (const float4*)(x + (size_t)b * 3072);
  for (int i = t; i < 768; i += 256) {
    float4 v = x4[i];
    int flat = i * 4, ic = flat >> 10, rem = flat & 1023, row = rem >> 5, col = rem & 31;
    float* d = &xpad[ic * 1156 + (row + 1) * 34 + (col + 1)];
    d[0] = v.x; d[1] = v.y; d[2] = v.z; d[3] = v.w;
  }
  __syncthreads();
  const int g = t & 15, oc = t >> 4;       // g: row-pair group, oc: out channel
  float w[27];
#pragma unroll
  for (int j = 0; j < 27; ++j) w[j] = gw[oc * 27 + j];
  const float bias = gb[oc];
  float sum = 0.f;
  const int r0 = 2 * g;
  for (int ct = 0; ct < 4; ++ct) {
    const int c0 = ct * 8;
    float val[16];
#pragma unroll
    for (int j = 0; j < 16; ++j) val[j] = bias;
#pragma unroll
    for (int ic = 0; ic < 3; ++ic) {
      float win[4][10];
#pragma unroll
      for (int rr = 0; rr < 4; ++rr) {
        const float2* p = (const float2*)&xpad[ic * 1156 + (r0 + rr) * 34 + c0];
#pragma unroll
        for (int q = 0; q < 5; ++q) { float2 v = p[q]; win[rr][2*q] = v.x; win[rr][2*q+1] = v.y; }
      }
#pragma unroll
      for (int ky = 0; ky < 3; ++ky)
#pragma unroll
      for (int kx = 0; kx < 3; ++kx) {
        const float wv = w[ic * 9 + ky * 3 + kx];
#pragma unroll
        for (int rr = 0; rr < 2; ++rr)
#pragma unroll
        for (int j = 0; j < 8; ++j)
          val[rr * 8 + j] += wv * win[rr + ky][j + kx];
      }
    }
#pragma unroll
    for (int j = 0; j < 16; ++j) sum += fmaxf(val[j], 0.f);
  }
  red[oc * 17 + g] = sum;
  __syncthreads();
  if (t < 16) {
    float s = 0.f;
#pragma unroll
    for (int g2 = 0; g2 < 16; ++g2) s += red[t * 17 + g2];
    pooled[(size_t)b * 16 + t] = s * (1.f / 1024.f);
  }
}

// ---------------- K2: router FC + softmax + top-1 + bucketing + prob sums ----------------
__global__ __launch_bounds__(256) void k_router_fc(const float* __restrict__ pooled,
    const float* __restrict__ gwfc, const float* __restrict__ gbfc,
    float* __restrict__ probs_out, int* __restrict__ eidx, float* __restrict__ ew,
    int* __restrict__ counts, int* __restrict__ order, float* __restrict__ psum) {
  __shared__ float ps[4];
  const int t = threadIdx.x;
  const int b = blockIdx.x * 256 + t;
  if (t < 4) ps[t] = 0.f;
  __syncthreads();
  const float* pl = pooled + (size_t)b * 16;
  float l[4];
#pragma unroll
  for (int j = 0; j < 4; ++j) {
    float s = gbfc[j];
#pragma unroll
    for (int i = 0; i < 16; ++i) s += pl[i] * gwfc[j * 16 + i];
    l[j] = s;
  }
  const float mx = fmaxf(fmaxf(l[0], l[1]), fmaxf(l[2], l[3]));
  float ex[4], ssum = 0.f;
#pragma unroll
  for (int j = 0; j < 4; ++j) { ex[j] = expf(l[j] - mx); ssum += ex[j]; }
  const float inv = 1.f / ssum;
  float p[4];
#pragma unroll
  for (int j = 0; j < 4; ++j) p[j] = ex[j] * inv;
  *(float4*)(probs_out + (size_t)b * 4) = make_float4(p[0], p[1], p[2], p[3]);
  int em = 0; float pm = p[0];
#pragma unroll
  for (int j = 1; j < 4; ++j) if (p[j] > pm) { pm = p[j]; em = j; }
  eidx[b] = em; ew[b] = pm;
  const int slot = atomicAdd(&counts[em], 1);
  order[em * B_N + slot] = b;
#pragma unroll
  for (int j = 0; j < 4; ++j) atomicAdd(&ps[j], p[j]);
  __syncthreads();
  if (t < 4) atomicAdd(&psum[t], ps[t]);
}

// ---------------- K3: expert conv1(3->32)+pool -> conv2(32->64)+pool, routed ----------------
__global__ __launch_bounds__(256) void k_experts_conv(const float* __restrict__ x,
    const float* __restrict__ w1g, const float* __restrict__ b1g,
    const float* __restrict__ w2g, const float* __restrict__ b2g,
    const int* __restrict__ eidx, float* __restrict__ h2g) {
  __shared__ __align__(16) float h1pad[32 * 18 * 18];   // 10368
  __shared__ __align__(16) float xpad[3 * 34 * 34];     // 3468
  const int b = blockIdx.x, t = threadIdx.x;
  const int e = __builtin_amdgcn_readfirstlane(eidx[b]);
  for (int i = t; i < 10368; i += 256) h1pad[i] = 0.f;
  for (int i = t; i < 3468; i += 256) xpad[i] = 0.f;
  __syncthreads();
  const float4* x4 = (const float4*)(x + (size_t)b * 3072);
  for (int i = t; i < 768; i += 256) {
    float4 v = x4[i];
    int flat = i * 4, ic = flat >> 10, rem = flat & 1023, row = rem >> 5, col = rem & 31;
    float* d = &xpad[ic * 1156 + (row + 1) * 34 + (col + 1)];
    d[0] = v.x; d[1] = v.y; d[2] = v.z; d[3] = v.w;
  }
  __syncthreads();
  // ---- conv1: thread = pooled position (16x16) ----
  {
    const int py = t >> 4, px = t & 15;
    float xw[3][4][4];
#pragma unroll
    for (int ic = 0; ic < 3; ++ic)
#pragma unroll
    for (int rr = 0; rr < 4; ++rr) {
      const float2* pp = (const float2*)&xpad[ic * 1156 + (2 * py + rr) * 34 + 2 * px];
      float2 a = pp[0], c = pp[1];
      xw[ic][rr][0] = a.x; xw[ic][rr][1] = a.y; xw[ic][rr][2] = c.x; xw[ic][rr][3] = c.y;
    }
    const float* w1 = w1g + e * 864;
    const float* b1 = b1g + e * 32;
    for (int oc = 0; oc < 32; ++oc) {
      const float bv = b1[oc];
      float a00 = bv, a01 = bv, a10 = bv, a11 = bv;
#pragma unroll
      for (int ic = 0; ic < 3; ++ic)
#pragma unroll
      for (int ky = 0; ky < 3; ++ky)
#pragma unroll
      for (int kx = 0; kx < 3; ++kx) {
        const float wv = w1[oc * 27 + ic * 9 + ky * 3 + kx];
        a00 += wv * xw[ic][ky][kx];
        a01 += wv * xw[ic][ky][kx + 1];
        a10 += wv * xw[ic][ky + 1][kx];
        a11 += wv * xw[ic][ky + 1][kx + 1];
      }
      float v = fmaxf(fmaxf(a00, a01), fmaxf(a10, a11));
      h1pad[oc * 324 + (py + 1) * 18 + (px + 1)] = fmaxf(v, 0.f);
    }
  }
  __syncthreads();
  // ---- conv2: lane = pooled pixel (8x8), wave = 16-oc chunk (weights wave-uniform -> s_loads) ----
  {
    const int wv_ = t >> 6, lane = t & 63;
    const int py = lane >> 3, px = lane & 7;
    const float* w2 = w2g + (size_t)e * 64 * 288;   // e*64*32*9
    const float* b2 = b2g + e * 64;
    float acc[16][4];
#pragma unroll
    for (int j = 0; j < 16; ++j) {
      const float bb = b2[16 * wv_ + j];
      acc[j][0] = bb; acc[j][1] = bb; acc[j][2] = bb; acc[j][3] = bb;
    }
    for (int ic = 0; ic < 32; ++ic) {
      float win[4][4];
#pragma unroll
      for (int rr = 0; rr < 4; ++rr) {
        const float2* pp = (const float2*)&h1pad[ic * 324 + (2 * py + rr) * 18 + 2 * px];
        float2 a = pp[0], c = pp[1];
        win[rr][0] = a.x; win[rr][1] = a.y; win[rr][2] = c.x; win[rr][3] = c.y;
      }
#pragma unroll
      for (int j = 0; j < 16; ++j) {
        const float* wp = w2 + ((16 * wv_ + j) * 32 + ic) * 9;
        const float w0 = wp[0], w1_ = wp[1], w2_ = wp[2], w3 = wp[3], w4 = wp[4],
                    w5 = wp[5], w6 = wp[6], w7 = wp[7], w8 = wp[8];
#pragma unroll
        for (int dy = 0; dy < 2; ++dy)
#pragma unroll
        for (int dx = 0; dx < 2; ++dx) {
          float s = acc[j][dy * 2 + dx];
          s += w0 * win[dy][dx]     + w1_ * win[dy][dx + 1]     + w2_ * win[dy][dx + 2];
          s += w3 * win[dy + 1][dx] + w4 * win[dy + 1][dx + 1]  + w5 * win[dy + 1][dx + 2];
          s += w6 * win[dy + 2][dx] + w7 * win[dy + 2][dx + 1]  + w8 * win[dy + 2][dx + 2];
          acc[j][dy * 2 + dx] = s;
        }
      }
    }
    float* outp = h2g + (size_t)b * 4096 + (size_t)(16 * wv_) * 64 + lane;
#pragma unroll
    for (int j = 0; j < 16; ++j) {
      float v = fmaxf(fmaxf(acc[j][0], acc[j][1]), fmaxf(acc[j][2], acc[j][3]));
      outp[j * 64] = fmaxf(v, 0.f);
    }
  }
}

// ---------------- K4: bucketed fc1(4096->128)+relu + fc2(128->10), scaled write ----------------
__global__ __launch_bounds__(256) void k_fc(const float* __restrict__ h2g,
    const float* __restrict__ w1g, const float* __restrict__ b1g,
    const float* __restrict__ w2g, const float* __restrict__ b2g,
    const int* __restrict__ counts, const int* __restrict__ order,
    const float* __restrict__ ew, float* __restrict__ outp) {
  const int bid = blockIdx.x;
  const int e = bid >> 8, tile = bid & 255;
  const int n = counts[e];
  const int base = tile * 16;
  if (base >= n) return;
  const int t = threadIdx.x;
  __shared__ int sb[16];
  __shared__ float wgt[16];
  __shared__ __align__(16) float4 fT[16][17];
  __shared__ float f1s[16 * 132];
  if (t < 16) {
    const int idx = base + t;
    const int s = order[e * B_N + ((idx < n) ? idx : base)];
    sb[t] = s; wgt[t] = ew[s];
  }
  __syncthreads();
  const int rowg = t & 3, colg = t >> 2;     // rows rowg*4..+3, cols colg*2..+1
  const float* w1 = w1g + (size_t)e * 524288;
  float acc[4][2];
#pragma unroll
  for (int i = 0; i < 4; ++i) { acc[i][0] = 0.f; acc[i][1] = 0.f; }
  const int row_l = t >> 4, seg = t & 15;
  const float4* fsrc = (const float4*)(h2g + (size_t)sb[row_l] * 4096);
  for (int kc = 0; kc < 4096; kc += 64) {
    fT[row_l][seg] = fsrc[(kc >> 2) + seg];
    __syncthreads();
    const float4* wrow0 = (const float4*)(w1 + (size_t)(colg * 2 + 0) * 4096 + kc);
    const float4* wrow1 = (const float4*)(w1 + (size_t)(colg * 2 + 1) * 4096 + kc);
#pragma unroll
    for (int kk = 0; kk < 16; ++kk) {
      const float4 wa = wrow0[kk], wb = wrow1[kk];
      const float4 f0 = fT[rowg * 4 + 0][kk];
      const float4 f1 = fT[rowg * 4 + 1][kk];
      const float4 f2 = fT[rowg * 4 + 2][kk];
      const float4 f3 = fT[rowg * 4 + 3][kk];
      acc[0][0] += f0.x*wa.x + f0.y*wa.y + f0.z*wa.z + f0.w*wa.w;
      acc[0][1] += f0.x*wb.x + f0.y*wb.y + f0.z*wb.z + f0.w*wb.w;
      acc[1][0] += f1.x*wa.x + f1.y*wa.y + f1.z*wa.z + f1.w*wa.w;
      acc[1][1] += f1.x*wb.x + f1.y*wb.y + f1.z*wb.z + f1.w*wb.w;
      acc[2][0] += f2.x*wa.x + f2.y*wa.y + f2.z*wa.z + f2.w*wa.w;
      acc[2][1] += f2.x*wb.x + f2.y*wb.y + f2.z*wb.z + f2.w*wb.w;
      acc[3][0] += f3.x*wa.x + f3.y*wa.y + f3.z*wa.z + f3.w*wa.w;
      acc[3][1] += f3.x*wb.x + f3.y*wb.y + f3.z*wb.z + f3.w*wb.w;
    }
    __syncthreads();
  }
  const float* b1 = b1g + e * 128;
#pragma unroll
  for (int i = 0; i < 4; ++i)
#pragma unroll
  for (int j = 0; j < 2; ++j) {
    const int r = rowg * 4 + i, c = colg * 2 + j;
    f1s[r * 132 + c] = fmaxf(acc[i][j] + b1[c], 0.f);
  }
  __syncthreads();
  int m = n - base; if (m > 16) m = 16;
  if (t < 160) {
    const int r = t / 10, o = t - r * 10;
    if (r < m) {
      const float* w2 = w2g + (e * 10 + o) * 128;
      float s = b2g[e * 10 + o];
#pragma unroll 8
      for (int c = 0; c < 128; ++c) s += f1s[r * 132 + c] * w2[c];
      outp[(size_t)sb[r] * 10 + o] = s * wgt[r];
    }
  }
}

// ---------------- K5: aux loss ----------------
__global__ void k_aux(const float* __restrict__ psum, float* __restrict__ outp) {
  if (threadIdx.x == 0 && blockIdx.x == 0) {
    float a = 0.f;
#pragma unroll
    for (int j = 0; j < 4; ++j) {
      const float mp = psum[j] * (1.f / 4096.f) - 0.25f;
      a += mp * mp;
    }
    outp[0] = a * 0.25f;
  }
}

extern "C" void kernel_launch(void* const* d_in, const int* in_sizes, int n_in,
                              void* d_out, int out_size, void* d_ws, size_t ws_size,
                              hipStream_t stream) {
  const float* x        = (const float*)d_in[0];
  const float* gw_conv  = (const float*)d_in[1];
  const float* gb_conv  = (const float*)d_in[2];
  const float* gw_fc    = (const float*)d_in[3];
  const float* gb_fc    = (const float*)d_in[4];
  const float* ew_conv1 = (const float*)d_in[5];
  const float* eb_conv1 = (const float*)d_in[6];
  const float* ew_conv2 = (const float*)d_in[7];
  const float* eb_conv2 = (const float*)d_in[8];
  const float* ew_fc1   = (const float*)d_in[9];
  const float* eb_fc1   = (const float*)d_in[10];
  const float* ew_fc2   = (const float*)d_in[11];
  const float* eb_fc2   = (const float*)d_in[12];
  float* out = (float*)d_out;
  float* ws  = (float*)d_ws;

  float* h2     = ws + H2_OFF;
  float* pooled = ws + POOLED_OFF;
  int*   eidx   = (int*)(ws + EIDX_OFF);
  float* ew     = ws + EW_OFF;
  int*   order  = (int*)(ws + ORDER_OFF);
  int*   counts = (int*)(ws + CNT_OFF);
  float* psum   = ws + PSUM_OFF;

  hipMemsetAsync(counts, 0, 32, stream);  // counts[4] + psum[4]
  k_router_conv<<<4096, 256, 0, stream>>>(x, gw_conv, gb_conv, pooled);
  k_router_fc<<<16, 256, 0, stream>>>(pooled, gw_fc, gb_fc, out + 40960, eidx, ew,
                                      counts, order, psum);
  k_experts_conv<<<4096, 256, 0, stream>>>(x, ew_conv1, eb_conv1, ew_conv2, eb_conv2,
                                           eidx, h2);
  k_fc<<<1024, 256, 0, stream>>>(h2, ew_fc1, eb_fc1, ew_fc2, eb_fc2,
                                 counts, order, ew, out);
  k_aux<<<1, 64, 0, stream>>>(psum, out + 57344);
}

// Round 3
// 627.038 us; speedup vs baseline: 2.3066x; 2.3066x over previous
//
#include <hip/hip_runtime.h>
#include <cstdint>
#include <cstddef>

#define B_N 4096
typedef short short8 __attribute__((ext_vector_type(8)));
typedef float f32x4 __attribute__((ext_vector_type(4)));

// ws layout (float units)
static constexpr size_t H2_OFF     = 0;                                  // 4096*4096 f
static constexpr size_t POOLED_OFF = (size_t)B_N * 4096;                 // B*16 f
static constexpr size_t EIDX_OFF   = POOLED_OFF + (size_t)B_N * 16;      // B int
static constexpr size_t EW_OFF     = EIDX_OFF + B_N;                     // B f
static constexpr size_t ORDER_OFF  = EW_OFF + B_N;                       // 4*B int
static constexpr size_t CNT_OFF    = ORDER_OFF + (size_t)4 * B_N;        // 4 int
static constexpr size_t PSUM_OFF   = CNT_OFF + 4;                        // 4 f
static constexpr size_t W2R_OFF    = PSUM_OFF + 4;                       // 73728 ushort (36864 f)

__device__ __forceinline__ unsigned int f2bf(float f) {
  unsigned int u = __float_as_uint(f);
  return (u + 0x7fffu + ((u >> 16) & 1u)) >> 16;   // RNE bf16
}

// ---------------- K0: repack conv2 weights -> bf16 [e][s][oc][ic] ----------------
__global__ __launch_bounds__(256) void k_repack_w2(const float* __restrict__ w2,
    unsigned short* __restrict__ w2r) {
  const int i = blockIdx.x * 256 + threadIdx.x;      // dst index
  if (i >= 4 * 9 * 64 * 32) return;
  const int ic = i & 31, j = i >> 5;
  const int oc = j & 63, j2 = j >> 6;
  const int s = j2 % 9, e = j2 / 9;
  const float v = w2[(((size_t)e * 64 + oc) * 32 + ic) * 9 + s];
  w2r[i] = (unsigned short)f2bf(v);
}

// ---------------- K1: router conv(3->16,SAME) + relu + global avg pool ----------------
__global__ __launch_bounds__(256) void k_router_conv(const float* __restrict__ x,
    const float* __restrict__ gw, const float* __restrict__ gb,
    float* __restrict__ pooled) {
  __shared__ __align__(16) float xpad[3 * 34 * 34];
  __shared__ float red[16 * 17];
  const int b = blockIdx.x, t = threadIdx.x;
  for (int i = t; i < 3 * 34 * 34; i += 256) xpad[i] = 0.f;
  __syncthreads();
  const float4* x4 = (const float4*)(x + (size_t)b * 3072);
  for (int i = t; i < 768; i += 256) {
    float4 v = x4[i];
    int flat = i * 4, ic = flat >> 10, rem = flat & 1023, row = rem >> 5, col = rem & 31;
    float* d = &xpad[ic * 1156 + (row + 1) * 34 + (col + 1)];
    d[0] = v.x; d[1] = v.y; d[2] = v.z; d[3] = v.w;
  }
  __syncthreads();
  const int g = t & 15, oc = t >> 4;
  float w[27];
#pragma unroll
  for (int j = 0; j < 27; ++j) w[j] = gw[oc * 27 + j];
  const float bias = gb[oc];
  float sum = 0.f;
  const int r0 = 2 * g;
  for (int ct = 0; ct < 4; ++ct) {
    const int c0 = ct * 8;
    float val[16];
#pragma unroll
    for (int j = 0; j < 16; ++j) val[j] = bias;
#pragma unroll
    for (int ic = 0; ic < 3; ++ic) {
      float win[4][10];
#pragma unroll
      for (int rr = 0; rr < 4; ++rr) {
        const float2* p = (const float2*)&xpad[ic * 1156 + (r0 + rr) * 34 + c0];
#pragma unroll
        for (int q = 0; q < 5; ++q) { float2 v = p[q]; win[rr][2*q] = v.x; win[rr][2*q+1] = v.y; }
      }
#pragma unroll
      for (int ky = 0; ky < 3; ++ky)
#pragma unroll
      for (int kx = 0; kx < 3; ++kx) {
        const float wv = w[ic * 9 + ky * 3 + kx];
#pragma unroll
        for (int rr = 0; rr < 2; ++rr)
#pragma unroll
        for (int j = 0; j < 8; ++j)
          val[rr * 8 + j] += wv * win[rr + ky][j + kx];
      }
    }
#pragma unroll
    for (int j = 0; j < 16; ++j) sum += fmaxf(val[j], 0.f);
  }
  red[oc * 17 + g] = sum;
  __syncthreads();
  if (t < 16) {
    float s = 0.f;
#pragma unroll
    for (int g2 = 0; g2 < 16; ++g2) s += red[t * 17 + g2];
    pooled[(size_t)b * 16 + t] = s * (1.f / 1024.f);
  }
}

// ---------------- K2: router FC + softmax + top-1 + bucketing + prob sums ----------------
__global__ __launch_bounds__(256) void k_router_fc(const float* __restrict__ pooled,
    const float* __restrict__ gwfc, const float* __restrict__ gbfc,
    float* __restrict__ probs_out, int* __restrict__ eidx, float* __restrict__ ew,
    int* __restrict__ counts, int* __restrict__ order, float* __restrict__ psum) {
  __shared__ float ps[4];
  const int t = threadIdx.x;
  const int b = blockIdx.x * 256 + t;
  if (t < 4) ps[t] = 0.f;
  __syncthreads();
  const float* pl = pooled + (size_t)b * 16;
  float l[4];
#pragma unroll
  for (int j = 0; j < 4; ++j) {
    float s = gbfc[j];
#pragma unroll
    for (int i = 0; i < 16; ++i) s += pl[i] * gwfc[j * 16 + i];
    l[j] = s;
  }
  const float mx = fmaxf(fmaxf(l[0], l[1]), fmaxf(l[2], l[3]));
  float ex[4], ssum = 0.f;
#pragma unroll
  for (int j = 0; j < 4; ++j) { ex[j] = expf(l[j] - mx); ssum += ex[j]; }
  const float inv = 1.f / ssum;
  float p[4];
#pragma unroll
  for (int j = 0; j < 4; ++j) p[j] = ex[j] * inv;
  *(float4*)(probs_out + (size_t)b * 4) = make_float4(p[0], p[1], p[2], p[3]);
  int em = 0; float pm = p[0];
#pragma unroll
  for (int j = 1; j < 4; ++j) if (p[j] > pm) { pm = p[j]; em = j; }
  eidx[b] = em; ew[b] = pm;
  const int slot = atomicAdd(&counts[em], 1);
  order[em * B_N + slot] = b;
#pragma unroll
  for (int j = 0; j < 4; ++j) atomicAdd(&ps[j], p[j]);
  __syncthreads();
  if (t < 4) atomicAdd(&psum[t], ps[t]);
}

// ---------------- K3: conv1 fp32 -> h1 bf16[pix][ic] in LDS -> conv2 via MFMA ----------------
__global__ __launch_bounds__(256) void k_experts_conv(const float* __restrict__ x,
    const float* __restrict__ w1g, const float* __restrict__ b1g,
    const unsigned short* __restrict__ w2r, const float* __restrict__ b2g,
    const int* __restrict__ eidx, float* __restrict__ h2g) {
  __shared__ __align__(16) float xpad[3 * 34 * 34];          // 13872 B
  __shared__ __align__(16) unsigned short h1s[18 * 18 * 32]; // 20736 B (reused as h2s)
  const int b = blockIdx.x, t = threadIdx.x;
  const int e = __builtin_amdgcn_readfirstlane(eidx[b]);
  {
    uint4 z4 = make_uint4(0, 0, 0, 0);
    uint4* z1 = (uint4*)h1s;
    for (int i = t; i < 1296; i += 256) z1[i] = z4;
    uint4* z2 = (uint4*)xpad;
    for (int i = t; i < 867; i += 256) z2[i] = z4;
  }
  __syncthreads();
  const float4* x4 = (const float4*)(x + (size_t)b * 3072);
  for (int i = t; i < 768; i += 256) {
    float4 v = x4[i];
    int flat = i * 4, ic = flat >> 10, rem = flat & 1023, row = rem >> 5, col = rem & 31;
    float* d = &xpad[ic * 1156 + (row + 1) * 34 + (col + 1)];
    d[0] = v.x; d[1] = v.y; d[2] = v.z; d[3] = v.w;
  }
  __syncthreads();
  // ---- conv1 (fp32): thread = pooled position (16x16), 32 oc -> bf16 packed ----
  {
    const int py = t >> 4, px = t & 15;
    float xw[3][4][4];
#pragma unroll
    for (int ic = 0; ic < 3; ++ic)
#pragma unroll
    for (int rr = 0; rr < 4; ++rr) {
      const float2* pp = (const float2*)&xpad[ic * 1156 + (2 * py + rr) * 34 + 2 * px];
      float2 a = pp[0], c = pp[1];
      xw[ic][rr][0] = a.x; xw[ic][rr][1] = a.y; xw[ic][rr][2] = c.x; xw[ic][rr][3] = c.y;
    }
    const float* w1 = w1g + e * 864;
    const float* b1 = b1g + e * 32;
    unsigned int hp[16];
    for (int oc = 0; oc < 32; oc += 2) {
      const float bv0 = b1[oc], bv1 = b1[oc + 1];
      float a00 = bv0, a01 = bv0, a10 = bv0, a11 = bv0;
      float c00 = bv1, c01 = bv1, c10 = bv1, c11 = bv1;
#pragma unroll
      for (int ic = 0; ic < 3; ++ic)
#pragma unroll
      for (int ky = 0; ky < 3; ++ky)
#pragma unroll
      for (int kx = 0; kx < 3; ++kx) {
        const float w0 = w1[oc * 27 + ic * 9 + ky * 3 + kx];
        const float w1v = w1[(oc + 1) * 27 + ic * 9 + ky * 3 + kx];
        const float p00 = xw[ic][ky][kx],     p01 = xw[ic][ky][kx + 1];
        const float p10 = xw[ic][ky + 1][kx], p11 = xw[ic][ky + 1][kx + 1];
        a00 += w0 * p00; a01 += w0 * p01; a10 += w0 * p10; a11 += w0 * p11;
        c00 += w1v * p00; c01 += w1v * p01; c10 += w1v * p10; c11 += w1v * p11;
      }
      const float v0 = fmaxf(fmaxf(fmaxf(a00, a01), fmaxf(a10, a11)), 0.f);
      const float v1 = fmaxf(fmaxf(fmaxf(c00, c01), fmaxf(c10, c11)), 0.f);
      hp[oc >> 1] = f2bf(v0) | (f2bf(v1) << 16);
    }
    uint4* dst = (uint4*)&h1s[((py + 1) * 18 + (px + 1)) * 32];
    const uint4* hs = (const uint4*)hp;
    dst[0] = hs[0]; dst[1] = hs[1]; dst[2] = hs[2]; dst[3] = hs[3];
  }
  __syncthreads();
  // ---- conv2: MFMA 16x16x32 bf16. wave = 16-oc chunk, m = 256 output pixels ----
  {
    const int lane = t & 63, wv = t >> 6;
    const int n16 = lane & 15, q = lane >> 4;
    const int oc = wv * 16 + n16;
    const float bias = b2g[e * 64 + oc];
    f32x4 acc[16];
#pragma unroll
    for (int mt = 0; mt < 16; ++mt) {
      acc[mt][0] = bias; acc[mt][1] = bias; acc[mt][2] = bias; acc[mt][3] = bias;
    }
    const unsigned short* wb = w2r + ((size_t)e * 9 * 64 + oc) * 32 + q * 8;
    for (int s = 0; s < 9; ++s) {
      const int ky = s / 3, kx = s - 3 * ky;
      const short8 bfrag = *(const short8*)(wb + s * 2048);
      const unsigned short* abase = &h1s[(ky * 18 + n16 + kx) * 32 + q * 8];
#pragma unroll
      for (int mt = 0; mt < 16; ++mt) {
        const short8 afrag = *(const short8*)(abase + mt * 576);   // 18*32
        acc[mt] = __builtin_amdgcn_mfma_f32_16x16x32_bf16(afrag, bfrag, acc[mt], 0, 0, 0);
      }
    }
    __syncthreads();                        // all MFMA reads of h1s done
    float* h2s = (float*)h1s;               // [oc][68] padded
#pragma unroll
    for (int u = 0; u < 8; ++u) {           // D rows m=quad*4+r (=ox), cols(oc)=lane&15
      f32x4 a = acc[2 * u], c = acc[2 * u + 1];
      const float p0 = fmaxf(fmaxf(a[0], a[1]), fmaxf(c[0], c[1]));
      const float p1 = fmaxf(fmaxf(a[2], a[3]), fmaxf(c[2], c[3]));
      float2 pv; pv.x = fmaxf(p0, 0.f); pv.y = fmaxf(p1, 0.f);
      *(float2*)&h2s[oc * 68 + u * 8 + 2 * q] = pv;   // pooled px = 2q,2q+1 ; py = u
    }
  }
  __syncthreads();
  {
    // write ALL 4096 floats: thread t writes 4 lane-contiguous float4s
    const float* h2s = (const float*)h1s;
    float* dst = h2g + (size_t)b * 4096;
#pragma unroll
    for (int j = 0; j < 4; ++j) {
      const int f = 4 * (t + 256 * j);          // flat float index, k = oc*64+py*8+px
      float4 v = *(const float4*)&h2s[(f >> 6) * 68 + (f & 63)];
      *(float4*)&dst[f] = v;
    }
  }
}

// ---------------- K4: bucketed fc1(4096->128)+relu + fc2(128->10), scaled write ----------------
__global__ __launch_bounds__(256) void k_fc(const float* __restrict__ h2g,
    const float* __restrict__ w1g, const float* __restrict__ b1g,
    const float* __restrict__ w2g, const float* __restrict__ b2g,
    const int* __restrict__ counts, const int* __restrict__ order,
    const float* __restrict__ ew, float* __restrict__ outp) {
  const int bid = blockIdx.x;
  const int e = bid >> 8, tile = bid & 255;
  const int n = counts[e];
  const int base = tile * 16;
  if (base >= n) return;
  const int t = threadIdx.x;
  __shared__ int sb[16];
  __shared__ float wgt[16];
  __shared__ __align__(16) float4 fT[16][17];
  __shared__ float f1s[16 * 132];
  if (t < 16) {
    const int idx = base + t;
    const int s = order[e * B_N + ((idx < n) ? idx : base)];
    sb[t] = s; wgt[t] = ew[s];
  }
  __syncthreads();
  const int rowg = t & 3, colg = t >> 2;
  const float* w1 = w1g + (size_t)e * 524288;
  float acc[4][2];
#pragma unroll
  for (int i = 0; i < 4; ++i) { acc[i][0] = 0.f; acc[i][1] = 0.f; }
  const int row_l = t >> 4, seg = t & 15;
  const float4* fsrc = (const float4*)(h2g + (size_t)sb[row_l] * 4096);
  for (int kc = 0; kc < 4096; kc += 64) {
    fT[row_l][seg] = fsrc[(kc >> 2) + seg];
    __syncthreads();
    const float4* wrow0 = (const float4*)(w1 + (size_t)(colg * 2 + 0) * 4096 + kc);
    const float4* wrow1 = (const float4*)(w1 + (size_t)(colg * 2 + 1) * 4096 + kc);
#pragma unroll
    for (int kk = 0; kk < 16; ++kk) {
      const float4 wa = wrow0[kk], wb = wrow1[kk];
      const float4 f0 = fT[rowg * 4 + 0][kk];
      const float4 f1 = fT[rowg * 4 + 1][kk];
      const float4 f2 = fT[rowg * 4 + 2][kk];
      const float4 f3 = fT[rowg * 4 + 3][kk];
      acc[0][0] += f0.x*wa.x + f0.y*wa.y + f0.z*wa.z + f0.w*wa.w;
      acc[0][1] += f0.x*wb.x + f0.y*wb.y + f0.z*wb.z + f0.w*wb.w;
      acc[1][0] += f1.x*wa.x + f1.y*wa.y + f1.z*wa.z + f1.w*wa.w;
      acc[1][1] += f1.x*wb.x + f1.y*wb.y + f1.z*wb.z + f1.w*wb.w;
      acc[2][0] += f2.x*wa.x + f2.y*wa.y + f2.z*wa.z + f2.w*wa.w;
      acc[2][1] += f2.x*wb.x + f2.y*wb.y + f2.z*wb.z + f2.w*wb.w;
      acc[3][0] += f3.x*wa.x + f3.y*wa.y + f3.z*wa.z + f3.w*wa.w;
      acc[3][1] += f3.x*wb.x + f3.y*wb.y + f3.z*wb.z + f3.w*wb.w;
    }
    __syncthreads();
  }
  const float* b1 = b1g + e * 128;
#pragma unroll
  for (int i = 0; i < 4; ++i)
#pragma unroll
  for (int j = 0; j < 2; ++j) {
    const int r = rowg * 4 + i, c = colg * 2 + j;
    f1s[r * 132 + c] = fmaxf(acc[i][j] + b1[c], 0.f);
  }
  __syncthreads();
  int m = n - base; if (m > 16) m = 16;
  if (t < 160) {
    const int r = t / 10, o = t - r * 10;
    if (r < m) {
      const float* w2 = w2g + (e * 10 + o) * 128;
      float s = b2g[e * 10 + o];
#pragma unroll 8
      for (int c = 0; c < 128; ++c) s += f1s[r * 132 + c] * w2[c];
      outp[(size_t)sb[r] * 10 + o] = s * wgt[r];
    }
  }
}

// ---------------- K5: aux loss ----------------
__global__ void k_aux(const float* __restrict__ psum, float* __restrict__ outp) {
  if (threadIdx.x == 0 && blockIdx.x == 0) {
    float a = 0.f;
#pragma unroll
    for (int j = 0; j < 4; ++j) {
      const float mp = psum[j] * (1.f / 4096.f) - 0.25f;
      a += mp * mp;
    }
    outp[0] = a * 0.25f;
  }
}

extern "C" void kernel_launch(void* const* d_in, const int* in_sizes, int n_in,
                              void* d_out, int out_size, void* d_ws, size_t ws_size,
                              hipStream_t stream) {
  const float* x        = (const float*)d_in[0];
  const float* gw_conv  = (const float*)d_in[1];
  const float* gb_conv  = (const float*)d_in[2];
  const float* gw_fc    = (const float*)d_in[3];
  const float* gb_fc    = (const float*)d_in[4];
  const float* ew_conv1 = (const float*)d_in[5];
  const float* eb_conv1 = (const float*)d_in[6];
  const float* ew_conv2 = (const float*)d_in[7];
  const float* eb_conv2 = (const float*)d_in[8];
  const float* ew_fc1   = (const float*)d_in[9];
  const float* eb_fc1   = (const float*)d_in[10];
  const float* ew_fc2   = (const float*)d_in[11];
  const float* eb_fc2   = (const float*)d_in[12];
  float* out = (float*)d_out;
  float* ws  = (float*)d_ws;

  float* h2     = ws + H2_OFF;
  float* pooled = ws + POOLED_OFF;
  int*   eidx   = (int*)(ws + EIDX_OFF);
  float* ew     = ws + EW_OFF;
  int*   order  = (int*)(ws + ORDER_OFF);
  int*   counts = (int*)(ws + CNT_OFF);
  float* psum   = ws + PSUM_OFF;
  unsigned short* w2r = (unsigned short*)(ws + W2R_OFF);

  hipMemsetAsync(counts, 0, 32, stream);  // counts[4] + psum[4]
  k_repack_w2<<<288, 256, 0, stream>>>(ew_conv2, w2r);
  k_router_conv<<<4096, 256, 0, stream>>>(x, gw_conv, gb_conv, pooled);
  k_router_fc<<<16, 256, 0, stream>>>(pooled, gw_fc, gb_fc, out + 40960, eidx, ew,
                                      counts, order, psum);
  k_experts_conv<<<4096, 256, 0, stream>>>(x, ew_conv1, eb_conv1, w2r, eb_conv2,
                                           eidx, h2);
  k_fc<<<1024, 256, 0, stream>>>(h2, ew_fc1, eb_fc1, ew_fc2, eb_fc2,
                                 counts, order, ew, out);
  k_aux<<<1, 64, 0, stream>>>(psum, out + 57344);
}

// Round 4
// 459.292 us; speedup vs baseline: 3.1491x; 1.3652x over previous
//
#include <hip/hip_runtime.h>
#include <cstdint>
#include <cstddef>

#define B_N 4096
typedef short short8 __attribute__((ext_vector_type(8)));
typedef float f32x4 __attribute__((ext_vector_type(4)));

// ws layout (float units)
static constexpr size_t H2B_OFF    = 0;                                  // 4096*4096 ushort = 8388608 f
static constexpr size_t POOLED_OFF = 8388608;                            // B*16 f
static constexpr size_t EIDX_OFF   = POOLED_OFF + (size_t)B_N * 16;      // B int
static constexpr size_t EW_OFF     = EIDX_OFF + B_N;                     // B f
static constexpr size_t ORDER_OFF  = EW_OFF + B_N;                       // 4*B int
static constexpr size_t CNT_OFF    = ORDER_OFF + (size_t)4 * B_N;        // 4 int
static constexpr size_t PSUM_OFF   = CNT_OFF + 4;                        // 4 f
static constexpr size_t W2R_OFF    = PSUM_OFF + 4;                       // 73728 ushort = 36864 f
static constexpr size_t W1R_OFF    = W2R_OFF + 36864;                    // 2097152 ushort = 1048576 f

__device__ __forceinline__ unsigned int f2bf(float f) {
  unsigned int u = __float_as_uint(f);
  return (u + 0x7fffu + ((u >> 16) & 1u)) >> 16;   // RNE bf16
}

// ---------------- K0a: repack conv2 weights -> bf16 [e][s][oc][ic] ----------------
__global__ __launch_bounds__(256) void k_repack_w2(const float* __restrict__ w2,
    unsigned short* __restrict__ w2r) {
  const int i = blockIdx.x * 256 + threadIdx.x;      // dst index
  if (i >= 4 * 9 * 64 * 32) return;
  const int ic = i & 31, j = i >> 5;
  const int oc = j & 63, j2 = j >> 6;
  const int s = j2 % 9, e = j2 / 9;
  const float v = w2[(((size_t)e * 64 + oc) * 32 + ic) * 9 + s];
  w2r[i] = (unsigned short)f2bf(v);
}

// ---------------- K0b: repack fc1 weights -> bf16 (same flat layout) ----------------
__global__ __launch_bounds__(256) void k_repack_w1(const float* __restrict__ w1,
    unsigned short* __restrict__ w1r) {
  const int i = blockIdx.x * 256 + threadIdx.x;      // float4 index
  const float4 v = ((const float4*)w1)[i];
  ushort4 u;
  u.x = (unsigned short)f2bf(v.x); u.y = (unsigned short)f2bf(v.y);
  u.z = (unsigned short)f2bf(v.z); u.w = (unsigned short)f2bf(v.w);
  *(ushort4*)(w1r + 4 * (size_t)i) = u;
}

// ---------------- K1: router conv(3->16,SAME) + relu + global avg pool ----------------
__global__ __launch_bounds__(256) void k_router_conv(const float* __restrict__ x,
    const float* __restrict__ gw, const float* __restrict__ gb,
    float* __restrict__ pooled) {
  __shared__ __align__(16) float xpad[3 * 34 * 34];
  __shared__ float red[16 * 17];
  const int b = blockIdx.x, t = threadIdx.x;
  for (int i = t; i < 3 * 34 * 34; i += 256) xpad[i] = 0.f;
  __syncthreads();
  const float4* x4 = (const float4*)(x + (size_t)b * 3072);
  for (int i = t; i < 768; i += 256) {
    float4 v = x4[i];
    int flat = i * 4, ic = flat >> 10, rem = flat & 1023, row = rem >> 5, col = rem & 31;
    float* d = &xpad[ic * 1156 + (row + 1) * 34 + (col + 1)];
    d[0] = v.x; d[1] = v.y; d[2] = v.z; d[3] = v.w;
  }
  __syncthreads();
  const int g = t & 15, oc = t >> 4;
  float w[27];
#pragma unroll
  for (int j = 0; j < 27; ++j) w[j] = gw[oc * 27 + j];
  const float bias = gb[oc];
  float sum = 0.f;
  const int r0 = 2 * g;
  for (int ct = 0; ct < 4; ++ct) {
    const int c0 = ct * 8;
    float val[16];
#pragma unroll
    for (int j = 0; j < 16; ++j) val[j] = bias;
#pragma unroll
    for (int ic = 0; ic < 3; ++ic) {
      float win[4][10];
#pragma unroll
      for (int rr = 0; rr < 4; ++rr) {
        const float2* p = (const float2*)&xpad[ic * 1156 + (r0 + rr) * 34 + c0];
#pragma unroll
        for (int q = 0; q < 5; ++q) { float2 v = p[q]; win[rr][2*q] = v.x; win[rr][2*q+1] = v.y; }
      }
#pragma unroll
      for (int ky = 0; ky < 3; ++ky)
#pragma unroll
      for (int kx = 0; kx < 3; ++kx) {
        const float wv = w[ic * 9 + ky * 3 + kx];
#pragma unroll
        for (int rr = 0; rr < 2; ++rr)
#pragma unroll
        for (int j = 0; j < 8; ++j)
          val[rr * 8 + j] += wv * win[rr + ky][j + kx];
      }
    }
#pragma unroll
    for (int j = 0; j < 16; ++j) sum += fmaxf(val[j], 0.f);
  }
  red[oc * 17 + g] = sum;
  __syncthreads();
  if (t < 16) {
    float s = 0.f;
#pragma unroll
    for (int g2 = 0; g2 < 16; ++g2) s += red[t * 17 + g2];
    pooled[(size_t)b * 16 + t] = s * (1.f / 1024.f);
  }
}

// ---------------- K2: router FC + softmax + top-1 + bucketing + prob sums ----------------
__global__ __launch_bounds__(256) void k_router_fc(const float* __restrict__ pooled,
    const float* __restrict__ gwfc, const float* __restrict__ gbfc,
    float* __restrict__ probs_out, int* __restrict__ eidx, float* __restrict__ ew,
    int* __restrict__ counts, int* __restrict__ order, float* __restrict__ psum) {
  __shared__ float ps[4];
  const int t = threadIdx.x;
  const int b = blockIdx.x * 256 + t;
  if (t < 4) ps[t] = 0.f;
  __syncthreads();
  const float* pl = pooled + (size_t)b * 16;
  float l[4];
#pragma unroll
  for (int j = 0; j < 4; ++j) {
    float s = gbfc[j];
#pragma unroll
    for (int i = 0; i < 16; ++i) s += pl[i] * gwfc[j * 16 + i];
    l[j] = s;
  }
  const float mx = fmaxf(fmaxf(l[0], l[1]), fmaxf(l[2], l[3]));
  float ex[4], ssum = 0.f;
#pragma unroll
  for (int j = 0; j < 4; ++j) { ex[j] = expf(l[j] - mx); ssum += ex[j]; }
  const float inv = 1.f / ssum;
  float p[4];
#pragma unroll
  for (int j = 0; j < 4; ++j) p[j] = ex[j] * inv;
  *(float4*)(probs_out + (size_t)b * 4) = make_float4(p[0], p[1], p[2], p[3]);
  int em = 0; float pm = p[0];
#pragma unroll
  for (int j = 1; j < 4; ++j) if (p[j] > pm) { pm = p[j]; em = j; }
  eidx[b] = em; ew[b] = pm;
  const int slot = atomicAdd(&counts[em], 1);
  order[em * B_N + slot] = b;
#pragma unroll
  for (int j = 0; j < 4; ++j) atomicAdd(&ps[j], p[j]);
  __syncthreads();
  if (t < 4) atomicAdd(&psum[t], ps[t]);
}

// ---------------- K3: conv1 fp32 -> h1 bf16 LDS -> conv2 MFMA -> h2 bf16 ----------------
__global__ __launch_bounds__(256) void k_experts_conv(const float* __restrict__ x,
    const float* __restrict__ w1g, const float* __restrict__ b1g,
    const unsigned short* __restrict__ w2r, const float* __restrict__ b2g,
    const int* __restrict__ eidx, unsigned short* __restrict__ h2b) {
  __shared__ __align__(16) float xpad[3 * 34 * 34];          // 13872 B
  __shared__ __align__(16) unsigned short h1s[18 * 18 * 32]; // 20736 B (reused as h2s fp32)
  const int b = blockIdx.x, t = threadIdx.x;
  const int e = __builtin_amdgcn_readfirstlane(eidx[b]);
  {
    uint4 z4 = make_uint4(0, 0, 0, 0);
    uint4* z1 = (uint4*)h1s;
    for (int i = t; i < 1296; i += 256) z1[i] = z4;
    uint4* z2 = (uint4*)xpad;
    for (int i = t; i < 867; i += 256) z2[i] = z4;
  }
  __syncthreads();
  const float4* x4 = (const float4*)(x + (size_t)b * 3072);
  for (int i = t; i < 768; i += 256) {
    float4 v = x4[i];
    int flat = i * 4, ic = flat >> 10, rem = flat & 1023, row = rem >> 5, col = rem & 31;
    float* d = &xpad[ic * 1156 + (row + 1) * 34 + (col + 1)];
    d[0] = v.x; d[1] = v.y; d[2] = v.z; d[3] = v.w;
  }
  __syncthreads();
  // ---- conv1 (fp32): thread = pooled position (16x16), 32 oc -> bf16 packed ----
  {
    const int py = t >> 4, px = t & 15;
    float xw[3][4][4];
#pragma unroll
    for (int ic = 0; ic < 3; ++ic)
#pragma unroll
    for (int rr = 0; rr < 4; ++rr) {
      const float2* pp = (const float2*)&xpad[ic * 1156 + (2 * py + rr) * 34 + 2 * px];
      float2 a = pp[0], c = pp[1];
      xw[ic][rr][0] = a.x; xw[ic][rr][1] = a.y; xw[ic][rr][2] = c.x; xw[ic][rr][3] = c.y;
    }
    const float* w1 = w1g + e * 864;
    const float* b1 = b1g + e * 32;
    unsigned int hp[16];
    for (int oc = 0; oc < 32; oc += 2) {
      const float bv0 = b1[oc], bv1 = b1[oc + 1];
      float a00 = bv0, a01 = bv0, a10 = bv0, a11 = bv0;
      float c00 = bv1, c01 = bv1, c10 = bv1, c11 = bv1;
#pragma unroll
      for (int ic = 0; ic < 3; ++ic)
#pragma unroll
      for (int ky = 0; ky < 3; ++ky)
#pragma unroll
      for (int kx = 0; kx < 3; ++kx) {
        const float w0 = w1[oc * 27 + ic * 9 + ky * 3 + kx];
        const float w1v = w1[(oc + 1) * 27 + ic * 9 + ky * 3 + kx];
        const float p00 = xw[ic][ky][kx],     p01 = xw[ic][ky][kx + 1];
        const float p10 = xw[ic][ky + 1][kx], p11 = xw[ic][ky + 1][kx + 1];
        a00 += w0 * p00; a01 += w0 * p01; a10 += w0 * p10; a11 += w0 * p11;
        c00 += w1v * p00; c01 += w1v * p01; c10 += w1v * p10; c11 += w1v * p11;
      }
      const float v0 = fmaxf(fmaxf(fmaxf(a00, a01), fmaxf(a10, a11)), 0.f);
      const float v1 = fmaxf(fmaxf(fmaxf(c00, c01), fmaxf(c10, c11)), 0.f);
      hp[oc >> 1] = f2bf(v0) | (f2bf(v1) << 16);
    }
    uint4* dst = (uint4*)&h1s[((py + 1) * 18 + (px + 1)) * 32];
    const uint4* hs = (const uint4*)hp;
    dst[0] = hs[0]; dst[1] = hs[1]; dst[2] = hs[2]; dst[3] = hs[3];
  }
  __syncthreads();
  // ---- conv2: MFMA 16x16x32 bf16. wave = 16-oc chunk, m = 256 output pixels ----
  {
    const int lane = t & 63, wv = t >> 6;
    const int n16 = lane & 15, q = lane >> 4;
    const int oc = wv * 16 + n16;
    const float bias = b2g[e * 64 + oc];
    f32x4 acc[16];
#pragma unroll
    for (int mt = 0; mt < 16; ++mt) {
      acc[mt][0] = bias; acc[mt][1] = bias; acc[mt][2] = bias; acc[mt][3] = bias;
    }
    const unsigned short* wb = w2r + ((size_t)e * 9 * 64 + oc) * 32 + q * 8;
    for (int s = 0; s < 9; ++s) {
      const int ky = s / 3, kx = s - 3 * ky;
      const short8 bfrag = *(const short8*)(wb + s * 2048);
      const unsigned short* abase = &h1s[(ky * 18 + n16 + kx) * 32 + q * 8];
#pragma unroll
      for (int mt = 0; mt < 16; ++mt) {
        const short8 afrag = *(const short8*)(abase + mt * 576);   // 18*32
        acc[mt] = __builtin_amdgcn_mfma_f32_16x16x32_bf16(afrag, bfrag, acc[mt], 0, 0, 0);
      }
    }
    __syncthreads();                        // all MFMA reads of h1s done
    float* h2s = (float*)h1s;               // [oc][68] padded
#pragma unroll
    for (int u = 0; u < 8; ++u) {           // D rows m=quad*4+r (=ox), cols(oc)=lane&15
      f32x4 a = acc[2 * u], c = acc[2 * u + 1];
      const float p0 = fmaxf(fmaxf(a[0], a[1]), fmaxf(c[0], c[1]));
      const float p1 = fmaxf(fmaxf(a[2], a[3]), fmaxf(c[2], c[3]));
      float2 pv; pv.x = fmaxf(p0, 0.f); pv.y = fmaxf(p1, 0.f);
      *(float2*)&h2s[oc * 68 + u * 8 + 2 * q] = pv;   // pooled px = 2q,2q+1 ; py = u
    }
  }
  __syncthreads();
  {
    // write all 4096 values as bf16: thread t writes 2 x (8 ushorts = 16 B)
    const float* h2s = (const float*)h1s;
    unsigned short* dst = h2b + (size_t)b * 4096;
#pragma unroll
    for (int j = 0; j < 2; ++j) {
      const int f = 8 * (t + 256 * j);          // flat k = oc*64+py*8+px
      const float* src = &h2s[(f >> 6) * 68 + (f & 63)];
      float4 v0 = *(const float4*)src;
      float4 v1 = *(const float4*)(src + 4);
      unsigned int p0 = f2bf(v0.x) | (f2bf(v0.y) << 16);
      unsigned int p1 = f2bf(v0.z) | (f2bf(v0.w) << 16);
      unsigned int p2 = f2bf(v1.x) | (f2bf(v1.y) << 16);
      unsigned int p3 = f2bf(v1.z) | (f2bf(v1.w) << 16);
      *(uint4*)(dst + f) = make_uint4(p0, p1, p2, p3);
    }
  }
}

// ---------------- K4: bucketed fc1 via bf16 MFMA + relu + fc2 fp32, scaled write ----------------
__global__ __launch_bounds__(256) void k_fc(const unsigned short* __restrict__ h2b,
    const unsigned short* __restrict__ w1r, const float* __restrict__ b1g,
    const float* __restrict__ w2g, const float* __restrict__ b2g,
    const int* __restrict__ counts, const int* __restrict__ order,
    const float* __restrict__ ew, float* __restrict__ outp) {
  const int bid = blockIdx.x;
  const int e = bid >> 8, tile = bid & 255;
  const int n = counts[e];
  const int base = tile * 16;
  if (base >= n) return;
  const int t = threadIdx.x;
  __shared__ int sb[16];
  __shared__ float wgt[16];
  __shared__ __align__(16) unsigned short As[16][264];   // 16 samples x 256 k, +8 pad
  __shared__ float f1s[16 * 132];
  if (t < 16) {
    const int idx = base + t;
    const int s = order[e * B_N + ((idx < n) ? idx : base)];
    sb[t] = s; wgt[t] = ew[s];
  }
  __syncthreads();
  const int lane = t & 63, wv = t >> 6;
  const int n16 = lane & 15, q = lane >> 4;
  const int oc0 = wv * 32 + n16;           // n-tile 2*wv
  const int oc1 = wv * 32 + 16 + n16;      // n-tile 2*wv+1
  const unsigned short* wb0 = w1r + ((size_t)(e * 128 + oc0)) * 4096 + q * 8;
  const unsigned short* wb1 = w1r + ((size_t)(e * 128 + oc1)) * 4096 + q * 8;
  f32x4 acc0 = {0.f, 0.f, 0.f, 0.f}, acc1 = {0.f, 0.f, 0.f, 0.f};
  const int ldrow = t >> 5, ldseg = t & 31;            // j=0: rows 0-7; j=1: rows 8-15
  for (int kc = 0; kc < 4096; kc += 256) {
#pragma unroll
    for (int j = 0; j < 2; ++j) {
      const int row = ldrow + 8 * j;
      uint4 v = *(const uint4*)(h2b + (size_t)sb[row] * 4096 + kc + ldseg * 8);
      *(uint4*)&As[row][ldseg * 8] = v;
    }
    __syncthreads();
#pragma unroll
    for (int ks = 0; ks < 8; ++ks) {
      const short8 af = *(const short8*)&As[n16][ks * 32 + q * 8];   // A[m=n16][k]
      const short8 bf0 = *(const short8*)(wb0 + kc + ks * 32);       // B[k][n=oc0]
      const short8 bf1 = *(const short8*)(wb1 + kc + ks * 32);
      acc0 = __builtin_amdgcn_mfma_f32_16x16x32_bf16(af, bf0, acc0, 0, 0, 0);
      acc1 = __builtin_amdgcn_mfma_f32_16x16x32_bf16(af, bf1, acc1, 0, 0, 0);
    }
    __syncthreads();
  }
  // C layout: row m = q*4+r (sample), col = n16 (oc)
  const float* b1 = b1g + e * 128;
  const float bb0 = b1[oc0], bb1 = b1[oc1];
#pragma unroll
  for (int r = 0; r < 4; ++r) {
    const int m = q * 4 + r;
    f1s[m * 132 + oc0] = fmaxf(acc0[r] + bb0, 0.f);
    f1s[m * 132 + oc1] = fmaxf(acc1[r] + bb1, 0.f);
  }
  __syncthreads();
  int m = n - base; if (m > 16) m = 16;
  if (t < 160) {
    const int r = t / 10, o = t - r * 10;
    if (r < m) {
      const float* w2 = w2g + (e * 10 + o) * 128;
      float s = b2g[e * 10 + o];
#pragma unroll 8
      for (int c = 0; c < 128; ++c) s += f1s[r * 132 + c] * w2[c];
      outp[(size_t)sb[r] * 10 + o] = s * wgt[r];
    }
  }
}

// ---------------- K5: aux loss ----------------
__global__ void k_aux(const float* __restrict__ psum, float* __restrict__ outp) {
  if (threadIdx.x == 0 && blockIdx.x == 0) {
    float a = 0.f;
#pragma unroll
    for (int j = 0; j < 4; ++j) {
      const float mp = psum[j] * (1.f / 4096.f) - 0.25f;
      a += mp * mp;
    }
    outp[0] = a * 0.25f;
  }
}

extern "C" void kernel_launch(void* const* d_in, const int* in_sizes, int n_in,
                              void* d_out, int out_size, void* d_ws, size_t ws_size,
                              hipStream_t stream) {
  const float* x        = (const float*)d_in[0];
  const float* gw_conv  = (const float*)d_in[1];
  const float* gb_conv  = (const float*)d_in[2];
  const float* gw_fc    = (const float*)d_in[3];
  const float* gb_fc    = (const float*)d_in[4];
  const float* ew_conv1 = (const float*)d_in[5];
  const float* eb_conv1 = (const float*)d_in[6];
  const float* ew_conv2 = (const float*)d_in[7];
  const float* eb_conv2 = (const float*)d_in[8];
  const float* ew_fc1   = (const float*)d_in[9];
  const float* eb_fc1   = (const float*)d_in[10];
  const float* ew_fc2   = (const float*)d_in[11];
  const float* eb_fc2   = (const float*)d_in[12];
  float* out = (float*)d_out;
  float* ws  = (float*)d_ws;

  unsigned short* h2b = (unsigned short*)(ws + H2B_OFF);
  float* pooled = ws + POOLED_OFF;
  int*   eidx   = (int*)(ws + EIDX_OFF);
  float* ew     = ws + EW_OFF;
  int*   order  = (int*)(ws + ORDER_OFF);
  int*   counts = (int*)(ws + CNT_OFF);
  float* psum   = ws + PSUM_OFF;
  unsigned short* w2r = (unsigned short*)(ws + W2R_OFF);
  unsigned short* w1r = (unsigned short*)(ws + W1R_OFF);

  hipMemsetAsync(counts, 0, 32, stream);  // counts[4] + psum[4]
  k_repack_w2<<<288, 256, 0, stream>>>(ew_conv2, w2r);
  k_repack_w1<<<2048, 256, 0, stream>>>(ew_fc1, w1r);
  k_router_conv<<<4096, 256, 0, stream>>>(x, gw_conv, gb_conv, pooled);
  k_router_fc<<<16, 256, 0, stream>>>(pooled, gw_fc, gb_fc, out + 40960, eidx, ew,
                                      counts, order, psum);
  k_experts_conv<<<4096, 256, 0, stream>>>(x, ew_conv1, eb_conv1, w2r, eb_conv2,
                                           eidx, h2b);
  k_fc<<<1024, 256, 0, stream>>>(h2b, w1r, eb_fc1, ew_fc2, eb_fc2,
                                 counts, order, ew, out);
  k_aux<<<1, 64, 0, stream>>>(psum, out + 57344);
}

// Round 5
// 325.374 us; speedup vs baseline: 4.4452x; 1.4116x over previous
//
#include <hip/hip_runtime.h>
#include <cstdint>
#include <cstddef>

#define B_N 4096
typedef short short8 __attribute__((ext_vector_type(8)));
typedef float f32x4 __attribute__((ext_vector_type(4)));

// ws layout (float units)
static constexpr size_t H2B_OFF    = 0;                                  // 4096*4096 ushort = 8388608 f
static constexpr size_t POOLED_OFF = 8388608;                            // B*16 f
static constexpr size_t EIDX_OFF   = POOLED_OFF + (size_t)B_N * 16;      // B int
static constexpr size_t EW_OFF     = EIDX_OFF + B_N;                     // B f
static constexpr size_t ORDER_OFF  = EW_OFF + B_N;                       // 4*B int
static constexpr size_t CNT_OFF    = ORDER_OFF + (size_t)4 * B_N;        // 4 int
static constexpr size_t PSUM_OFF   = CNT_OFF + 4;                        // 4 f
static constexpr size_t W2R_OFF    = PSUM_OFF + 4;                       // 73728 ushort = 36864 f
static constexpr size_t W1R_OFF    = W2R_OFF + 36864;                    // 2097152 ushort = 1048576 f
static constexpr size_t W1C_OFF    = W1R_OFF + 1048576;                  // 4096 ushort = 2048 f

__device__ __forceinline__ unsigned int f2bf(float f) {
  unsigned int u = __float_as_uint(f);
  return (u + 0x7fffu + ((u >> 16) & 1u)) >> 16;   // RNE bf16
}

// ---------------- K0a: repack conv2 weights -> bf16 [e][s][oc][ic] ----------------
__global__ __launch_bounds__(256) void k_repack_w2(const float* __restrict__ w2,
    unsigned short* __restrict__ w2r) {
  const int i = blockIdx.x * 256 + threadIdx.x;      // dst index
  if (i >= 4 * 9 * 64 * 32) return;
  const int ic = i & 31, j = i >> 5;
  const int oc = j & 63, j2 = j >> 6;
  const int s = j2 % 9, e = j2 / 9;
  const float v = w2[(((size_t)e * 64 + oc) * 32 + ic) * 9 + s];
  w2r[i] = (unsigned short)f2bf(v);
}

// ---------------- K0b: repack fc1 weights -> bf16 (same flat layout) ----------------
__global__ __launch_bounds__(256) void k_repack_w1(const float* __restrict__ w1,
    unsigned short* __restrict__ w1r) {
  const int i = blockIdx.x * 256 + threadIdx.x;      // float4 index
  const float4 v = ((const float4*)w1)[i];
  ushort4 u;
  u.x = (unsigned short)f2bf(v.x); u.y = (unsigned short)f2bf(v.y);
  u.z = (unsigned short)f2bf(v.z); u.w = (unsigned short)f2bf(v.w);
  *(ushort4*)(w1r + 4 * (size_t)i) = u;
}

// ---------------- K0c: repack conv1 weights -> bf16 B-frag layout [e][nt][q][n16][j] ----------------
__global__ __launch_bounds__(256) void k_repack_w1c(const float* __restrict__ w1,
    unsigned short* __restrict__ w1c) {
  const int i = blockIdx.x * 256 + threadIdx.x;      // [0, 4096)
  if (i >= 4096) return;
  const int j = i & 7, n16 = (i >> 3) & 15, q = (i >> 7) & 3, nt = (i >> 9) & 1, e = i >> 10;
  const int k = q * 8 + j;
  float v = 0.f;
  if (k < 27) {
    const int ky = k / 9, c = k % 9, kx = c / 3, ic = c % 3;
    const int oc = nt * 16 + n16;
    v = w1[((e * 32 + oc) * 3 + ic) * 9 + ky * 3 + kx];
  }
  w1c[i] = (unsigned short)f2bf(v);
}

// ---------------- K1: router conv(3->16,SAME) + relu + global avg pool (fp32 exact) ----------------
__global__ __launch_bounds__(256) void k_router_conv(const float* __restrict__ x,
    const float* __restrict__ gw, const float* __restrict__ gb,
    float* __restrict__ pooled) {
  __shared__ __align__(16) float xpad[3 * 34 * 34];
  __shared__ float red[16 * 17];
  const int b = blockIdx.x, t = threadIdx.x;
  for (int i = t; i < 3 * 34 * 34; i += 256) xpad[i] = 0.f;
  __syncthreads();
  const float4* x4 = (const float4*)(x + (size_t)b * 3072);
  for (int i = t; i < 768; i += 256) {
    float4 v = x4[i];
    int flat = i * 4, ic = flat >> 10, rem = flat & 1023, row = rem >> 5, col = rem & 31;
    float* d = &xpad[ic * 1156 + (row + 1) * 34 + (col + 1)];
    d[0] = v.x; d[1] = v.y; d[2] = v.z; d[3] = v.w;
  }
  __syncthreads();
  const int g = t & 15, oc = t >> 4;
  float w[27];
#pragma unroll
  for (int j = 0; j < 27; ++j) w[j] = gw[oc * 27 + j];
  const float bias = gb[oc];
  float sum = 0.f;
  const int r0 = 2 * g;
  for (int ct = 0; ct < 4; ++ct) {
    const int c0 = ct * 8;
    float val[16];
#pragma unroll
    for (int j = 0; j < 16; ++j) val[j] = bias;
#pragma unroll
    for (int ic = 0; ic < 3; ++ic) {
      float win[4][10];
#pragma unroll
      for (int rr = 0; rr < 4; ++rr) {
        const float2* p = (const float2*)&xpad[ic * 1156 + (r0 + rr) * 34 + c0];
#pragma unroll
        for (int qq = 0; qq < 5; ++qq) { float2 v = p[qq]; win[rr][2*qq] = v.x; win[rr][2*qq+1] = v.y; }
      }
#pragma unroll
      for (int ky = 0; ky < 3; ++ky)
#pragma unroll
      for (int kx = 0; kx < 3; ++kx) {
        const float wv = w[ic * 9 + ky * 3 + kx];
#pragma unroll
        for (int rr = 0; rr < 2; ++rr)
#pragma unroll
        for (int j = 0; j < 8; ++j)
          val[rr * 8 + j] += wv * win[rr + ky][j + kx];
      }
    }
#pragma unroll
    for (int j = 0; j < 16; ++j) sum += fmaxf(val[j], 0.f);
  }
  red[oc * 17 + g] = sum;
  __syncthreads();
  if (t < 16) {
    float s = 0.f;
#pragma unroll
    for (int g2 = 0; g2 < 16; ++g2) s += red[t * 17 + g2];
    pooled[(size_t)b * 16 + t] = s * (1.f / 1024.f);
  }
}

// ---------------- K2: router FC + softmax + top-1 + bucketing + prob sums ----------------
__global__ __launch_bounds__(256) void k_router_fc(const float* __restrict__ pooled,
    const float* __restrict__ gwfc, const float* __restrict__ gbfc,
    float* __restrict__ probs_out, int* __restrict__ eidx, float* __restrict__ ew,
    int* __restrict__ counts, int* __restrict__ order, float* __restrict__ psum) {
  __shared__ float ps[4];
  const int t = threadIdx.x;
  const int b = blockIdx.x * 256 + t;
  if (t < 4) ps[t] = 0.f;
  __syncthreads();
  const float* pl = pooled + (size_t)b * 16;
  float l[4];
#pragma unroll
  for (int j = 0; j < 4; ++j) {
    float s = gbfc[j];
#pragma unroll
    for (int i = 0; i < 16; ++i) s += pl[i] * gwfc[j * 16 + i];
    l[j] = s;
  }
  const float mx = fmaxf(fmaxf(l[0], l[1]), fmaxf(l[2], l[3]));
  float ex[4], ssum = 0.f;
#pragma unroll
  for (int j = 0; j < 4; ++j) { ex[j] = expf(l[j] - mx); ssum += ex[j]; }
  const float inv = 1.f / ssum;
  float p[4];
#pragma unroll
  for (int j = 0; j < 4; ++j) p[j] = ex[j] * inv;
  *(float4*)(probs_out + (size_t)b * 4) = make_float4(p[0], p[1], p[2], p[3]);
  int em = 0; float pm = p[0];
#pragma unroll
  for (int j = 1; j < 4; ++j) if (p[j] > pm) { pm = p[j]; em = j; }
  eidx[b] = em; ew[b] = pm;
  const int slot = atomicAdd(&counts[em], 1);
  order[em * B_N + slot] = b;
#pragma unroll
  for (int j = 0; j < 4; ++j) atomicAdd(&ps[j], p[j]);
  __syncthreads();
  if (t < 4) atomicAdd(&psum[t], ps[t]);
}

// ---- conv1 A-fragment gather from ic-interleaved fp32 image ----
__device__ __forceinline__ short8 gather_a(const float* __restrict__ base,
                                           const int* goff, bool isq1, bool isq3) {
  float v[8];
#pragma unroll
  for (int t4 = 0; t4 < 4; ++t4) {
    v[2 * t4]     = base[goff[t4]];
    v[2 * t4 + 1] = base[goff[t4] + 1];
  }
  const float pv = base[102];          // patch: p=9 (row 1, c 0) for q==1 lanes
  v[1] = isq1 ? pv : v[1];
  v[3] = isq3 ? 0.f : v[3];            // p>=27 zero padding (q==3, j>=3)
  v[4] = isq3 ? 0.f : v[4];
  v[5] = isq3 ? 0.f : v[5];
  v[6] = isq3 ? 0.f : v[6];
  v[7] = isq3 ? 0.f : v[7];
  union { unsigned u[4]; short8 s; } r;
#pragma unroll
  for (int j = 0; j < 4; ++j) {
    const unsigned lo = (__float_as_uint(v[2 * j]) + 0x8000u) >> 16;        // rnd-half-up bf16
    const unsigned hi = (__float_as_uint(v[2 * j + 1]) + 0x8000u) & 0xffff0000u;
    r.u[j] = lo | hi;
  }
  return r.s;
}

// ---------------- K3: conv1 MFMA (im2col) -> h1 bf16 LDS -> conv2 MFMA -> h2 bf16 ----------------
__global__ __launch_bounds__(256, 3) void k_experts_conv(const float* __restrict__ x,
    const unsigned short* __restrict__ w1c, const float* __restrict__ b1g,
    const unsigned short* __restrict__ w2r, const float* __restrict__ b2g,
    const int* __restrict__ eidx, unsigned short* __restrict__ h2b) {
  __shared__ __align__(16) float xpi[3572];                  // [34 rows][34 cols][3 ic] +pad, 14288 B
  __shared__ __align__(16) unsigned short h1s[18 * 18 * 32]; // 20736 B (reused as h2s fp32 [64][68])
  const int b = blockIdx.x, t = threadIdx.x;
  const int e = __builtin_amdgcn_readfirstlane(eidx[b]);
  {
    uint4 z4 = make_uint4(0, 0, 0, 0);
    uint4* z1 = (uint4*)h1s;
    for (int i = t; i < 1296; i += 256) z1[i] = z4;
    uint4* z2 = (uint4*)xpi;
    for (int i = t; i < 893; i += 256) z2[i] = z4;
  }
  __syncthreads();
  const float4* x4 = (const float4*)(x + (size_t)b * 3072);
  for (int i = t; i < 768; i += 256) {
    float4 v = x4[i];
    int flat = i * 4, ic = flat >> 10, rem = flat & 1023, row = rem >> 5, col = rem & 31;
    float* d = &xpi[(row + 1) * 102 + (col + 1) * 3 + ic];
    d[0] = v.x; d[3] = v.y; d[6] = v.z; d[9] = v.w;
  }
  __syncthreads();
  const int lane = t & 63, wv = t >> 6;
  const int n16 = lane & 15, q = lane >> 4;
  // ---- conv1: MFMA 16x16x32, K=27(+pad), M=pixel col, N=32 oc ----
  {
    const bool isq1 = (q == 1), isq3 = (q == 3);
    const short8 wb0 = *(const short8*)(w1c + (((e * 2 + 0) * 4 + q) * 16 + n16) * 8);
    const short8 wb1 = *(const short8*)(w1c + (((e * 2 + 1) * 4 + q) * 16 + n16) * 8);
    const float bias0 = b1g[e * 32 + n16];
    const float bias1 = b1g[e * 32 + 16 + n16];
    int goff[4];
#pragma unroll
    for (int t4 = 0; t4 < 4; ++t4) {
      const int p0 = q * 8 + 2 * t4;
      const int r = (p0 * 939) >> 13;        // p0/9 for p0<32
      goff[t4] = r * 102 + (p0 - 9 * r);
    }
    for (int pid = 0; pid < 8; ++pid) {
      const int pairid = wv * 8 + pid;
      const int yp = pairid >> 1, xh = pairid & 1;
      const float* baseA = &xpi[(2 * yp) * 102 + (xh * 16 + n16) * 3];
      const short8 afA = gather_a(baseA, goff, isq1, isq3);
      const short8 afB = gather_a(baseA + 102, goff, isq1, isq3);
      f32x4 aA0 = {bias0, bias0, bias0, bias0}, aA1 = {bias1, bias1, bias1, bias1};
      f32x4 aB0 = aA0, aB1 = aA1;
      aA0 = __builtin_amdgcn_mfma_f32_16x16x32_bf16(afA, wb0, aA0, 0, 0, 0);
      aA1 = __builtin_amdgcn_mfma_f32_16x16x32_bf16(afA, wb1, aA1, 0, 0, 0);
      aB0 = __builtin_amdgcn_mfma_f32_16x16x32_bf16(afB, wb0, aB0, 0, 0, 0);
      aB1 = __builtin_amdgcn_mfma_f32_16x16x32_bf16(afB, wb1, aB1, 0, 0, 0);
      // 2x2 maxpool + relu -> h1s[pix][ic] bf16
      const int px = xh * 8 + 2 * q;
      unsigned short* hw = &h1s[((yp + 1) * 18 + (px + 1)) * 32];
      const float p00 = fmaxf(fmaxf(fmaxf(aA0[0], aA0[1]), fmaxf(aB0[0], aB0[1])), 0.f);
      const float p01 = fmaxf(fmaxf(fmaxf(aA0[2], aA0[3]), fmaxf(aB0[2], aB0[3])), 0.f);
      const float p10 = fmaxf(fmaxf(fmaxf(aA1[0], aA1[1]), fmaxf(aB1[0], aB1[1])), 0.f);
      const float p11 = fmaxf(fmaxf(fmaxf(aA1[2], aA1[3]), fmaxf(aB1[2], aB1[3])), 0.f);
      hw[n16]           = (unsigned short)f2bf(p00);
      hw[16 + n16]      = (unsigned short)f2bf(p10);
      hw[32 + n16]      = (unsigned short)f2bf(p01);
      hw[32 + 16 + n16] = (unsigned short)f2bf(p11);
    }
  }
  __syncthreads();
  // ---- conv2: wave = 4 rows x all 64 oc; B streamed from global (L2) with prefetch ----
  {
    const unsigned short* wbase = w2r + (size_t)e * 18432 + n16 * 32 + q * 8;
    float bz[4];
#pragma unroll
    for (int nt = 0; nt < 4; ++nt) bz[nt] = b2g[e * 64 + nt * 16 + n16];
    f32x4 acc[4][4];
#pragma unroll
    for (int mt4 = 0; mt4 < 4; ++mt4)
#pragma unroll
      for (int nt = 0; nt < 4; ++nt) {
        acc[mt4][nt][0] = bz[nt]; acc[mt4][nt][1] = bz[nt];
        acc[mt4][nt][2] = bz[nt]; acc[mt4][nt][3] = bz[nt];
      }
    short8 Bc[4];
#pragma unroll
    for (int nt = 0; nt < 4; ++nt) Bc[nt] = *(const short8*)(wbase + nt * 512);
#pragma unroll
    for (int s = 0; s < 9; ++s) {
      const int ky = s / 3, kx = s % 3;
      short8 Bn[4];
      if (s < 8) {
#pragma unroll
        for (int nt = 0; nt < 4; ++nt)
          Bn[nt] = *(const short8*)(wbase + (s + 1) * 2048 + nt * 512);
      }
#pragma unroll
      for (int mt4 = 0; mt4 < 4; ++mt4) {
        const int mt = wv * 4 + mt4;
        const short8 af = *(const short8*)&h1s[((mt + ky) * 18 + n16 + kx) * 32 + q * 8];
#pragma unroll
        for (int nt = 0; nt < 4; ++nt)
          acc[mt4][nt] = __builtin_amdgcn_mfma_f32_16x16x32_bf16(af, Bc[nt], acc[mt4][nt], 0, 0, 0);
      }
      if (s < 8) {
#pragma unroll
        for (int nt = 0; nt < 4; ++nt) Bc[nt] = Bn[nt];
      }
    }
    __syncthreads();                        // all MFMA reads of h1s done
    float* h2s = (float*)h1s;               // [oc][68]
#pragma unroll
    for (int u2 = 0; u2 < 2; ++u2) {
      const int py = wv * 2 + u2;
#pragma unroll
      for (int nt = 0; nt < 4; ++nt) {
        const f32x4 a = acc[2 * u2][nt], c = acc[2 * u2 + 1][nt];
        float2 pv;
        pv.x = fmaxf(fmaxf(fmaxf(a[0], a[1]), fmaxf(c[0], c[1])), 0.f);
        pv.y = fmaxf(fmaxf(fmaxf(a[2], a[3]), fmaxf(c[2], c[3])), 0.f);
        *(float2*)&h2s[(nt * 16 + n16) * 68 + py * 8 + 2 * q] = pv;
      }
    }
  }
  __syncthreads();
  {
    // write all 4096 values as bf16: thread t writes 2 x (8 ushorts = 16 B)
    const float* h2s = (const float*)h1s;
    unsigned short* dst = h2b + (size_t)b * 4096;
#pragma unroll
    for (int j = 0; j < 2; ++j) {
      const int f = 8 * (t + 256 * j);          // flat k = oc*64+py*8+px
      const float* src = &h2s[(f >> 6) * 68 + (f & 63)];
      float4 v0 = *(const float4*)src;
      float4 v1 = *(const float4*)(src + 4);
      unsigned int p0 = f2bf(v0.x) | (f2bf(v0.y) << 16);
      unsigned int p1 = f2bf(v0.z) | (f2bf(v0.w) << 16);
      unsigned int p2 = f2bf(v1.x) | (f2bf(v1.y) << 16);
      unsigned int p3 = f2bf(v1.z) | (f2bf(v1.w) << 16);
      *(uint4*)(dst + f) = make_uint4(p0, p1, p2, p3);
    }
  }
}

// ---------------- K4: bucketed fc1 via bf16 MFMA + relu + fc2 fp32, scaled write ----------------
__global__ __launch_bounds__(256) void k_fc(const unsigned short* __restrict__ h2b,
    const unsigned short* __restrict__ w1r, const float* __restrict__ b1g,
    const float* __restrict__ w2g, const float* __restrict__ b2g,
    const int* __restrict__ counts, const int* __restrict__ order,
    const float* __restrict__ ew, float* __restrict__ outp) {
  const int bid = blockIdx.x;
  const int e = bid >> 8, tile = bid & 255;
  const int n = counts[e];
  const int base = tile * 16;
  if (base >= n) return;
  const int t = threadIdx.x;
  __shared__ int sb[16];
  __shared__ float wgt[16];
  __shared__ __align__(16) unsigned short As[16][264];   // 16 samples x 256 k, +8 pad
  __shared__ float f1s[16 * 132];
  if (t < 16) {
    const int idx = base + t;
    const int s = order[e * B_N + ((idx < n) ? idx : base)];
    sb[t] = s; wgt[t] = ew[s];
  }
  __syncthreads();
  const int lane = t & 63, wv = t >> 6;
  const int n16 = lane & 15, q = lane >> 4;
  const int oc0 = wv * 32 + n16;           // n-tile 2*wv
  const int oc1 = wv * 32 + 16 + n16;      // n-tile 2*wv+1
  const unsigned short* wb0 = w1r + ((size_t)(e * 128 + oc0)) * 4096 + q * 8;
  const unsigned short* wb1 = w1r + ((size_t)(e * 128 + oc1)) * 4096 + q * 8;
  f32x4 acc0 = {0.f, 0.f, 0.f, 0.f}, acc1 = {0.f, 0.f, 0.f, 0.f};
  const int ldrow = t >> 5, ldseg = t & 31;            // j=0: rows 0-7; j=1: rows 8-15
  for (int kc = 0; kc < 4096; kc += 256) {
#pragma unroll
    for (int j = 0; j < 2; ++j) {
      const int row = ldrow + 8 * j;
      uint4 v = *(const uint4*)(h2b + (size_t)sb[row] * 4096 + kc + ldseg * 8);
      *(uint4*)&As[row][ldseg * 8] = v;
    }
    __syncthreads();
#pragma unroll
    for (int ks = 0; ks < 8; ++ks) {
      const short8 af = *(const short8*)&As[n16][ks * 32 + q * 8];   // A[m=n16][k]
      const short8 bf0 = *(const short8*)(wb0 + kc + ks * 32);       // B[k][n=oc0]
      const short8 bf1 = *(const short8*)(wb1 + kc + ks * 32);
      acc0 = __builtin_amdgcn_mfma_f32_16x16x32_bf16(af, bf0, acc0, 0, 0, 0);
      acc1 = __builtin_amdgcn_mfma_f32_16x16x32_bf16(af, bf1, acc1, 0, 0, 0);
    }
    __syncthreads();
  }
  // C layout: row m = q*4+r (sample), col = n16 (oc)
  const float* b1 = b1g + e * 128;
  const float bb0 = b1[oc0], bb1 = b1[oc1];
#pragma unroll
  for (int r = 0; r < 4; ++r) {
    const int m = q * 4 + r;
    f1s[m * 132 + oc0] = fmaxf(acc0[r] + bb0, 0.f);
    f1s[m * 132 + oc1] = fmaxf(acc1[r] + bb1, 0.f);
  }
  __syncthreads();
  int m = n - base; if (m > 16) m = 16;
  if (t < 160) {
    const int r = t / 10, o = t - r * 10;
    if (r < m) {
      const float* w2 = w2g + (e * 10 + o) * 128;
      float s = b2g[e * 10 + o];
#pragma unroll 8
      for (int c = 0; c < 128; ++c) s += f1s[r * 132 + c] * w2[c];
      outp[(size_t)sb[r] * 10 + o] = s * wgt[r];
    }
  }
}

// ---------------- K5: aux loss ----------------
__global__ void k_aux(const float* __restrict__ psum, float* __restrict__ outp) {
  if (threadIdx.x == 0 && blockIdx.x == 0) {
    float a = 0.f;
#pragma unroll
    for (int j = 0; j < 4; ++j) {
      const float mp = psum[j] * (1.f / 4096.f) - 0.25f;
      a += mp * mp;
    }
    outp[0] = a * 0.25f;
  }
}

extern "C" void kernel_launch(void* const* d_in, const int* in_sizes, int n_in,
                              void* d_out, int out_size, void* d_ws, size_t ws_size,
                              hipStream_t stream) {
  const float* x        = (const float*)d_in[0];
  const float* gw_conv  = (const float*)d_in[1];
  const float* gb_conv  = (const float*)d_in[2];
  const float* gw_fc    = (const float*)d_in[3];
  const float* gb_fc    = (const float*)d_in[4];
  const float* ew_conv1 = (const float*)d_in[5];
  const float* eb_conv1 = (const float*)d_in[6];
  const float* ew_conv2 = (const float*)d_in[7];
  const float* eb_conv2 = (const float*)d_in[8];
  const float* ew_fc1   = (const float*)d_in[9];
  const float* eb_fc1   = (const float*)d_in[10];
  const float* ew_fc2   = (const float*)d_in[11];
  const float* eb_fc2   = (const float*)d_in[12];
  float* out = (float*)d_out;
  float* ws  = (float*)d_ws;

  unsigned short* h2b = (unsigned short*)(ws + H2B_OFF);
  float* pooled = ws + POOLED_OFF;
  int*   eidx   = (int*)(ws + EIDX_OFF);
  float* ew     = ws + EW_OFF;
  int*   order  = (int*)(ws + ORDER_OFF);
  int*   counts = (int*)(ws + CNT_OFF);
  float* psum   = ws + PSUM_OFF;
  unsigned short* w2r = (unsigned short*)(ws + W2R_OFF);
  unsigned short* w1r = (unsigned short*)(ws + W1R_OFF);
  unsigned short* w1c = (unsigned short*)(ws + W1C_OFF);

  hipMemsetAsync(counts, 0, 32, stream);  // counts[4] + psum[4]
  k_repack_w2<<<288, 256, 0, stream>>>(ew_conv2, w2r);
  k_repack_w1<<<2048, 256, 0, stream>>>(ew_fc1, w1r);
  k_repack_w1c<<<16, 256, 0, stream>>>(ew_conv1, w1c);
  k_router_conv<<<4096, 256, 0, stream>>>(x, gw_conv, gb_conv, pooled);
  k_router_fc<<<16, 256, 0, stream>>>(pooled, gw_fc, gb_fc, out + 40960, eidx, ew,
                                      counts, order, psum);
  k_experts_conv<<<4096, 256, 0, stream>>>(x, w1c, eb_conv1, w2r, eb_conv2,
                                           eidx, h2b);
  k_fc<<<1024, 256, 0, stream>>>(h2b, w1r, eb_fc1, ew_fc2, eb_fc2,
                                 counts, order, ew, out);
  k_aux<<<1, 64, 0, stream>>>(psum, out + 57344);
}